// Round 11
// baseline (211.763 us; speedup 1.0000x reference)
//
#include <hip/hip_runtime.h>

#define NT 128
#define SS 512
#define MID 256
#define PW 132                         // padded per-wave column stride (floats)

// workspace layout (floats)
#define WSF_P 0                        // [256][128] forward alpha-hat at t=255
#define WSF_M (256 * 128)              // [256] M0f
#define WSF_S (WSF_M + 256)            // [256] Sf
#define WSB_P (WSF_S + 256)            // [256][128] backward q-hat at t=255
#define WSB_S (WSB_P + 256 * 128)      // [256] Sb

__device__ __forceinline__ float rdlane(float v, int lane) {
    return __int_as_float(__builtin_amdgcn_readlane(__float_as_int(v), lane));
}
__device__ __forceinline__ int fexp_of(float x) {
    return (int)((__float_as_uint(x) >> 23) & 0xFFu) - 127;
}
// barrier draining only LDS ops — global prefetches stay in flight
__device__ __forceinline__ void lds_barrier() {
    asm volatile("s_waitcnt lgkmcnt(0)\n\ts_barrier" ::: "memory");
}

__global__ void zero_out_kernel(float* out) { out[0] = 0.0f; }

// R10 (fb split + anchor-K + setprio + balanced prologue) with ONE change:
// mov-free matvec. Table split into eTx/eTy float arrays; each row is two
// scalar fmaf(q, eT, acc) -> v_fmac_f32 with the wave-uniform readlane value
// as the single legal SGPR source. Kills the {q,q} pair-building v_movs
// (up to 64/step/wave) that the f32x2 form forced.
__global__ __launch_bounds__(256, 2) void crf_fb_kernel(
    const float* __restrict__ emissions,        // [B, S, NT] f32
    const int* __restrict__ tags,               // [B, S]
    const unsigned char* __restrict__ mask,     // [B, S]
    const float* __restrict__ trans,            // [NT, NT] f32
    float* __restrict__ out,                    // [1] f32
    float* __restrict__ ws)                     // workspace
{
    const bool fw  = (blockIdx.x < 256);
    const int b    = blockIdx.x & 255;
    const int tid  = threadIdx.x;               // 0..255
    const int l    = tid & 63;
    const int w    = tid >> 6;                  // wave 0..3: rows/states 32w..32w+31
    const int st   = (w << 5) + (l & 31);       // owned state (dup on lane halves)

    __shared__ float pbuf[2][4 * PW];           // [parity][wave*PW + col]
    __shared__ int   kslot;
    __shared__ float redf[4];
    __shared__ float redg[4];

    const float*         emB = emissions + (size_t)b * SS * NT;
    const int*           tgB = tags + b * SS;
    const unsigned char* mkB = mask + b * SS;

    // ---- gold score: BACKWARD blocks only (balances prologues) ----
    float gold = 0.0f;
    if (!fw) {
        for (int t = tid; t < SS; t += 256) {
            int tg   = tgB[t];
            float mk = mkB[t] ? 1.0f : 0.0f;
            float a  = emB[(size_t)t * NT + tg];
            if (t > 0) a += trans[tgB[t - 1] * NT + tg];
            gold += a * mk;
        }
    }

    // ---- expT slice, split x/y: fwd row-block, bwd transposed ----
    float eTx[32], eTy[32];
    if (fw) {
        #pragma unroll
        for (int r = 0; r < 32; r++) {
            const float* row = trans + (size_t)((w << 5) + r) * NT;
            eTx[r] = __expf(row[l]);
            eTy[r] = __expf(row[l + 64]);
        }
    } else {
        #pragma unroll
        for (int r = 0; r < 32; r++) {          // eT[{l,l+64}][32w+r]
            eTx[r] = __expf(trans[(size_t)l * NT + (w << 5) + r]);
            eTy[r] = __expf(trans[(size_t)(l + 64) * NT + (w << 5) + r]);
        }
    }

    // ---- init state + emission pipeline (4 deep, exp 2 steps off-chain) ----
    float p, M0 = 0.0f, S = 0.0f;
    int K = 0, kv_own = 0;
    float ex_o, ex_e, pd_o, pd_e;
    if (fw) {
        float a0 = emB[st];
        float v = a0;
        #pragma unroll
        for (int o = 16; o > 0; o >>= 1) v = fmaxf(v, __shfl_xor(v, o));
        if (l == 0) redf[w] = v;
        __syncthreads();
        M0 = fmaxf(fmaxf(redf[0], redf[1]), fmaxf(redf[2], redf[3]));
        p  = __expf(a0 - M0);
        ex_o = __expf(emB[(size_t)1 * NT + st]);
        ex_e = __expf(emB[(size_t)2 * NT + st]);
        pd_o = emB[(size_t)3 * NT + st];
        pd_e = emB[(size_t)4 * NT + st];
    } else {
        p = 1.0f;                               // q_511 = 1
        ex_o = __expf(emB[(size_t)511 * NT + st]);
        ex_e = __expf(emB[(size_t)510 * NT + st]);
        pd_o = emB[(size_t)509 * NT + st];
        pd_e = emB[(size_t)508 * NT + st];
    }

    // matvec over own 32 rows: readlane (SGPR) + 2 scalar-src fmac per row.
    auto mv = [&](int q, bool kw, float src) -> float {
        float A0x = 0.f, A1x = 0.f, A2x = 0.f, A3x = 0.f;
        float A0y = 0.f, A1y = 0.f, A2y = 0.f, A3y = 0.f;
        __builtin_amdgcn_s_setprio(1);
        #pragma unroll
        for (int r = 0; r < 32; r += 4) {
            float q0 = rdlane(src, r + 0);
            float q1 = rdlane(src, r + 1);
            float q2 = rdlane(src, r + 2);
            float q3 = rdlane(src, r + 3);
            A0x = fmaf(q0, eTx[r + 0], A0x);  A0y = fmaf(q0, eTy[r + 0], A0y);
            A1x = fmaf(q1, eTx[r + 1], A1x);  A1y = fmaf(q1, eTy[r + 1], A1y);
            A2x = fmaf(q2, eTx[r + 2], A2x);  A2y = fmaf(q2, eTy[r + 2], A2y);
            A3x = fmaf(q3, eTx[r + 3], A3x);  A3y = fmaf(q3, eTy[r + 3], A3y);
        }
        __builtin_amdgcn_s_setprio(0);
        float sx = (A0x + A1x) + (A2x + A3x);   // partial col l
        float sy = (A0y + A1y) + (A2y + A3y);   // partial col l+64
        pbuf[q][w * PW + l]      = sx;
        pbuf[q][w * PW + l + 64] = sy;
        if (kw && tid == 0) kslot = kv_own;     // anchor K rides the barrier
        lds_barrier();                          // lgkm-only: vmcnt untouched
        return (pbuf[q][0 * PW + st] + pbuf[q][1 * PW + st]) +
               (pbuf[q][2 * PW + st] + pbuf[q][3 * PW + st]);
    };
    auto rotF = [&](int t, float& pd, float& ex) {
        float nr = pd;
        int tn = t + 4; if (tn > SS - 1) tn = SS - 1;
        pd = emB[(size_t)tn * NT + st];
        ex = __expf(nr);
    };
    auto rotB = [&](int t, float& pd, float& ex) {
        float nr = pd;
        int tn = t - 3; if (tn < 0) tn = 0;
        pd = emB[(size_t)tn * NT + st];
        ex = __expf(nr);
    };

    // ---- recursion: groups of 4 steps; anchor rescale at sub-step 0 ----
    if (fw) {
        #pragma unroll 1
        for (int t = 1; t < MID; t += 4) {
            {   // sub 0 (parity 1): apply K, propose next kv (state-0 anchor)
                float sn = mv(1, false, p) * ex_o;
                p = ldexpf(sn, -K);
                S += (float)K;
                kv_own = fexp_of(p);            // only tid 0's value is consumed
                rotF(t, pd_o, ex_o);
            }
            if (t + 1 < MID) {   // sub 1 (parity 0): K anchor piggyback
                float sn = mv(0, true, p) * ex_e;
                K = kslot;                      // uniform read, off-chain
                p = sn;
                rotF(t + 1, pd_e, ex_e);
            }
            if (t + 2 < MID) { p = mv(1, false, p) * ex_o; rotF(t + 2, pd_o, ex_o); }
            if (t + 3 < MID) { p = mv(0, false, p) * ex_e; rotF(t + 3, pd_e, ex_e); }
        }
    } else {
        #pragma unroll 1
        for (int t = 510; t >= 258; t -= 4) {   // 64 full groups: q_510 .. q_255
            {   // sub 0 (parity 1)
                float sn = mv(1, false, p * ex_o);
                p = ldexpf(sn, -K);
                S += (float)K;
                kv_own = fexp_of(p);
                rotB(t, pd_o, ex_o);
            }
            {   // sub 1 (parity 0)
                float sn = mv(0, true, p * ex_e);
                K = kslot;
                p = sn;
                rotB(t - 1, pd_e, ex_e);
            }
            { p = mv(1, false, p * ex_o); rotB(t - 2, pd_o, ex_o); }
            { p = mv(0, false, p * ex_e); rotB(t - 3, pd_e, ex_e); }
        }
    }

    // ---- epilogue: publish vectors + scales; backward also reduces gold ----
    if (l < 32) {
        ws[(fw ? WSF_P : WSB_P) + b * NT + st] = p;
    }
    if (fw) {
        if (tid == 0) {
            ws[WSF_M + b] = M0;
            ws[WSF_S + b] = S;
        }
    } else {
        float g = gold;
        #pragma unroll
        for (int o = 32; o > 0; o >>= 1) g += __shfl_xor(g, o);
        if (l == 0) redg[w] = g;
        __syncthreads();
        if (tid == 0) {
            ws[WSB_S + b] = S;
            float gt = (redg[0] + redg[1]) + (redg[2] + redg[3]);
            atomicAdd(out, -gt);
        }
    }
}

// partition_b = M0f + (Sf+Sb)*ln2 + log( sum_i alpha_hat[i] * q_hat[i] )
__global__ __launch_bounds__(64, 1) void crf_combine_kernel(
    const float* __restrict__ ws, float* __restrict__ out)
{
    const int b = blockIdx.x;
    const int l = threadIdx.x;                  // 0..63
    const float* pf = ws + WSF_P + b * NT;
    const float* pb = ws + WSB_P + b * NT;
    float d = pf[l] * pb[l] + pf[l + 64] * pb[l + 64];
    #pragma unroll
    for (int o = 32; o > 0; o >>= 1) d += __shfl_xor(d, o);
    if (l == 0) {
        float part = ws[WSF_M + b] +
                     (ws[WSF_S + b] + ws[WSB_S + b]) * 0.69314718055994531f +
                     __logf(d);
        atomicAdd(out, part);
    }
}

extern "C" void kernel_launch(void* const* d_in, const int* in_sizes, int n_in,
                              void* d_out, int out_size, void* d_ws, size_t ws_size,
                              hipStream_t stream) {
    const float*         emissions = (const float*)d_in[0];
    const int*           tags      = (const int*)d_in[1];
    const unsigned char* mask      = (const unsigned char*)d_in[2];
    const float*         trans     = (const float*)d_in[3];
    float*               out       = (float*)d_out;
    float*               ws        = (float*)d_ws;

    zero_out_kernel<<<1, 1, 0, stream>>>(out);
    crf_fb_kernel<<<512, 256, 0, stream>>>(emissions, tags, mask, trans, out, ws);
    crf_combine_kernel<<<256, 64, 0, stream>>>(ws, out);
}